// Round 15
// baseline (314.139 us; speedup 1.0000x reference)
//
#include <hip/hip_runtime.h>
#include <cstdint>
#include <cmath>

#define NTH 256

namespace {

typedef _Float16 half8  __attribute__((ext_vector_type(8)));
typedef _Float16 half4v __attribute__((ext_vector_type(4)));
typedef float    float4v __attribute__((ext_vector_type(4)));

constexpr int IMG_W   = 100;
constexpr int NS      = 64;
constexpr int D_PTS   = 63;
constexpr int D_DIR   = 27;
constexpr int HID     = 256;
constexpr int HID_DIR = 128;

constexpr int ENC_H = 72;    // enc stride (halfs), 144B rows (16B-aligned)
constexpr int H_S   = 264;   // hbuf stride (halfs), 528B rows
constexpr int HD_S  = 136;   // hd stride (halfs), 272B rows

// Packed fragments [ks][tile][lane][8]; lane data identical for A- or B-side use
// (A[m=lr][k=lq*8+j] vs B[k=lq*8+j][n=lr] have the same lane indexing).
//   w1p:  ks=2, 16 tiles -> 16384 halfs @ 0
//   w2p:  ks=8, 16 tiles -> 65536 halfs @ 16384
//   wdp:  ks=8, 9 tiles (8 dir + sigma) -> 36864 halfs @ 81920
//   wrgb: ks=4, 1 tile   ->  2048 halfs @ 118784
constexpr int W1P_OFF  = 0;
constexpr int W2P_OFF  = 16384;
constexpr int WDP_OFF  = 81920;
constexpr int WRGB_OFF = 118784;
constexpr int WPACK_HALFS = 120832;    // 241664 bytes

__global__ __launch_bounds__(NTH)
void prepack(const float* __restrict__ w1, const float* __restrict__ w2,
             const float* __restrict__ wd, const float* __restrict__ wsig,
             const float* __restrict__ wrgb, _Float16* __restrict__ wp)
{
    const int idx = blockIdx.x * NTH + threadIdx.x;
    if (idx >= WPACK_HALFS) return;
    const int j    = idx & 7;
    const int lane = (idx >> 3) & 63;
    const int kloc = (lane >> 4) * 8 + j;
    const int lr   = lane & 15;
    float v = 0.0f;
    if (idx < W2P_OFF) {                               // w1 (K pad 63->64)
        const int nt = (idx >> 9) & 15, ks = idx >> 13;
        const int k = ks * 32 + kloc;
        if (k < D_PTS) v = w1[k * HID + nt * 16 + lr];
    } else if (idx < WDP_OFF) {                        // w2
        const int t = idx - W2P_OFF;
        const int nt = (t >> 9) & 15, ks = t >> 13;
        v = w2[(ks * 32 + kloc) * HID + nt * 16 + lr];
    } else if (idx < WRGB_OFF) {                       // w_dir (K=256) + sigma col
        const int t = idx - WDP_OFF;
        const int q = t >> 9;
        const int ks = q / 9, tile = q - 9 * ks;
        const int k = ks * 32 + kloc;
        if (tile < 8) v = wd[k * HID_DIR + tile * 16 + lr];
        else if (lr == 0) v = wsig[k];
    } else {                                           // w_rgb (N=3 in 16-tile)
        const int t = idx - WRGB_OFF;
        const int ks = t >> 9;
        const int k = ks * 32 + kloc;
        if (lr < 3) v = wrgb[k * 3 + lr];
    }
    wp[idx] = (_Float16)v;
}

// Fallback gathers (no workspace): 8 scalar fp32 loads + cvt.
__device__ __forceinline__ half8 bf_w(const float* __restrict__ W, int ldN,
                                      int kbase, int n, int kmax) {
    half8 b;
    #pragma unroll
    for (int j = 0; j < 8; ++j) {
        const int k = kbase + j;
        b[j] = (_Float16)((k < kmax) ? W[k * ldN + n] : 0.0f);
    }
    return b;
}
__device__ __forceinline__ half8 bf_sig(const float* __restrict__ ws, int kbase, int lr) {
    half8 b;
    #pragma unroll
    for (int j = 0; j < 8; ++j)
        b[j] = (_Float16)((lr == 0) ? ws[kbase + j] : 0.0f);
    return b;
}
__device__ __forceinline__ half8 bf_rgb(const float* __restrict__ wr, int kbase, int lr) {
    half8 b;
    #pragma unroll
    for (int j = 0; j < 8; ++j)
        b[j] = (_Float16)((lr < 3) ? wr[(kbase + j) * 3 + lr] : 0.0f);
    return b;
}

template<bool PACKED>
__global__ __launch_bounds__(NTH, 3)
void nerf_fused(const float* __restrict__ c2w,
                const float* __restrict__ t_rand,
                const float* __restrict__ w1,  const float* __restrict__ b1,
                const float* __restrict__ w2,  const float* __restrict__ b2,
                const float* __restrict__ w_sig, const float* __restrict__ b_sig,
                const float* __restrict__ w_dir, const float* __restrict__ b_dir,
                const float* __restrict__ w_rgb, const float* __restrict__ b_rgb,
                const _Float16* __restrict__ wpack,
                float* __restrict__ out)
{
    __shared__ __align__(16) unsigned char scrA[NS * ENC_H * 2];       // 9216 B
    _Float16* encH = reinterpret_cast<_Float16*>(scrA);
    double*   encD = reinterpret_cast<double*>(scrA);                  //  512 B
    double*   h1d  = reinterpret_cast<double*>(scrA + 512);            // 2048 B
    double*   h2d  = reinterpret_cast<double*>(scrA + 2560);           // 2048 B
    __shared__ __align__(16) _Float16 hbuf[NS * H_S];                  // 33792 B
    __shared__ __align__(16) float dbv[HID_DIR];                       // dir tail+bias
    __shared__ float  zbuf[NS];
    __shared__ double zd[NS];
    __shared__ float  encdir[32];
    __shared__ float  sigb[NS];
    __shared__ float  rgbb[NS * 3];

    const int tid  = threadIdx.x;
    const int ray  = blockIdx.x;
    const int lane = tid & 63;
    const int wv   = tid >> 6;
    const int lr   = lane & 15;
    const int lq   = lane >> 4;

    const half8* wp8 = reinterpret_cast<const half8*>(wpack);

    // ---- per-ray setup ----
    const int pj = ray / IMG_W;
    const int pi = ray - pj * IMG_W;
    const float dx = ((float)pi - 50.0f) / 86.6f;
    const float dy = -(((float)pj) - 50.0f) / 86.6f;
    const float rd0 = dx * c2w[0] + dy * c2w[1] - c2w[2];
    const float rd1 = dx * c2w[4] + dy * c2w[5] - c2w[6];
    const float rd2 = dx * c2w[8] + dy * c2w[9] - c2w[10];
    const float ro0 = c2w[3], ro1 = c2w[7], ro2 = c2w[11];
    const float nrm = sqrtf(rd0 * rd0 + rd1 * rd1 + rd2 * rd2);
    const float vd0 = rd0 / nrm, vd1 = rd1 / nrm, vd2 = rd2 / nrm;

    // ---- z: np.linspace-style f64 chain (t[63]=1 exact) ----
    if (tid < NS) {
        const int s = tid;
        const double delta = 1.0 / 63.0;
        const double ts = (s == 63) ? 1.0 : (double)s * delta;
        const double zs = 2.0 * (1.0 - ts) + 6.0 * ts;
        double lower, upper;
        if (s == 0) { lower = zs; }
        else { const double tm = (double)(s - 1) * delta;
               const double zm = 2.0 * (1.0 - tm) + 6.0 * tm; lower = 0.5 * (zm + zs); }
        if (s == 63) { upper = zs; }
        else { const double tp = (s + 1 == 63) ? 1.0 : (double)(s + 1) * delta;
               const double zp = 2.0 * (1.0 - tp) + 6.0 * tp; upper = 0.5 * (zs + zp); }
        const double zz = lower + (upper - lower) * (double)t_rand[s];
        zd[s]   = zz;
        zbuf[s] = (float)zz;
    }
    if (tid < 32) {
        float v = 0.0f;
        if (tid < D_DIR) {
            const int f = tid;
            if (f < 3) {
                v = (f == 0) ? vd0 : ((f == 1) ? vd1 : vd2);
            } else {
                const int ff = f - 3;
                const int l = ff / 6;
                const int r = ff - 6 * l;
                const int c = r % 3;
                const float x = ((c == 0) ? vd0 : ((c == 1) ? vd1 : vd2)) * (float)(1 << l);
                v = (r < 3) ? sinf(x) : cosf(x);
            }
        }
        encdir[tid] = v;
    }
    __syncthreads();

    // ---- enc_pts via double-angle recurrence ----
    if (tid < 192) {
        const int s = tid / 3;
        const int c = tid - 3 * s;
        const float zv = zbuf[s];
        const float p = (c == 0) ? (ro0 + rd0 * zv) : ((c == 1) ? (ro1 + rd1 * zv) : (ro2 + rd2 * zv));
        _Float16* row = &encH[s * ENC_H];
        row[c] = (_Float16)p;
        float sl = sinf(p), cl = cosf(p);
        row[3 + c] = (_Float16)sl;
        row[6 + c] = (_Float16)cl;
        #pragma unroll
        for (int l = 1; l < 10; ++l) {
            const float s2 = 2.0f * sl * cl;
            const float c2 = 1.0f - 2.0f * sl * sl;
            row[3 + 6 * l + c]     = (_Float16)s2;
            row[3 + 6 * l + 3 + c] = (_Float16)c2;
            sl = s2; cl = c2;
        }
    }
    if (tid < 64) encH[tid * ENC_H + 63] = (_Float16)0.0f;   // K-pad col
    // dir tail + bias: db[n] = b_dir[n] + encdir . w_dir[256..282][n]  (ray-uniform)
    if (tid < HID_DIR) {
        float d = b_dir[tid];
        for (int t = 0; t < D_DIR; ++t)
            d += encdir[t] * w_dir[(HID + t) * HID_DIR + tid];
        dbv[tid] = d;
    }
    __syncthreads();

    // ======== layer 1 (MFMA, swapped operands): C'[neuron][sample] ========
    {
        float4v acc[4][4];   // [nt][st]
        #pragma unroll
        for (int nt = 0; nt < 4; ++nt)
            #pragma unroll
            for (int st = 0; st < 4; ++st) acc[nt][st] = float4v{0.f, 0.f, 0.f, 0.f};

        #pragma unroll
        for (int ks = 0; ks < 2; ++ks) {
            half8 h[4];
            #pragma unroll
            for (int st = 0; st < 4; ++st)
                h[st] = *reinterpret_cast<const half8*>(&encH[(st * 16 + lr) * ENC_H + ks * 32 + lq * 8]);
            #pragma unroll
            for (int nt = 0; nt < 4; ++nt) {
                const int tile = wv * 4 + nt;
                const half8 w = PACKED
                    ? wp8[(W1P_OFF >> 3) + (ks * 16 + tile) * 64 + lane]
                    : bf_w(w1, HID, ks * 32 + lq * 8, tile * 16 + lr, D_PTS);
                #pragma unroll
                for (int st = 0; st < 4; ++st)
                    acc[nt][st] = __builtin_amdgcn_mfma_f32_16x16x32_f16(w, h[st], acc[nt][st], 0, 0, 0);
            }
        }
        // epilogue: thread holds neurons nb..nb+3 of sample st*16+lr -> one b64 write
        #pragma unroll
        for (int nt = 0; nt < 4; ++nt) {
            const int nb = (wv * 4 + nt) * 16 + lq * 4;
            const float4v bb = *reinterpret_cast<const float4v*>(&b1[nb]);
            #pragma unroll
            for (int st = 0; st < 4; ++st) {
                half4v hv;
                #pragma unroll
                for (int r = 0; r < 4; ++r)
                    hv[r] = (_Float16)fmaxf(acc[nt][st][r] + bb[r], 0.0f);
                *reinterpret_cast<half4v*>(&hbuf[(st * 16 + lr) * H_S + nb]) = hv;
            }
        }
    }
    __syncthreads();

    // ======== layer 2 (MFMA): H2 = relu(H1 @ w2 + b2) ========
    {
        float4v acc[4][4];
        #pragma unroll
        for (int nt = 0; nt < 4; ++nt)
            #pragma unroll
            for (int st = 0; st < 4; ++st) acc[nt][st] = float4v{0.f, 0.f, 0.f, 0.f};

        for (int ks = 0; ks < 8; ++ks) {
            half8 h[4];
            #pragma unroll
            for (int st = 0; st < 4; ++st)
                h[st] = *reinterpret_cast<const half8*>(&hbuf[(st * 16 + lr) * H_S + ks * 32 + lq * 8]);
            #pragma unroll
            for (int nt = 0; nt < 4; ++nt) {
                const int tile = wv * 4 + nt;
                const half8 w = PACKED
                    ? wp8[(W2P_OFF >> 3) + (ks * 16 + tile) * 64 + lane]
                    : bf_w(w2, HID, ks * 32 + lq * 8, tile * 16 + lr, 1 << 30);
                #pragma unroll
                for (int st = 0; st < 4; ++st)
                    acc[nt][st] = __builtin_amdgcn_mfma_f32_16x16x32_f16(w, h[st], acc[nt][st], 0, 0, 0);
            }
        }
        __syncthreads();   // all H1 reads complete before in-place overwrite
        #pragma unroll
        for (int nt = 0; nt < 4; ++nt) {
            const int nb = (wv * 4 + nt) * 16 + lq * 4;
            const float4v bb = *reinterpret_cast<const float4v*>(&b2[nb]);
            #pragma unroll
            for (int st = 0; st < 4; ++st) {
                half4v hv;
                #pragma unroll
                for (int r = 0; r < 4; ++r)
                    hv[r] = (_Float16)fmaxf(acc[nt][st][r] + bb[r], 0.0f);
                *reinterpret_cast<half4v*>(&hbuf[(st * 16 + lr) * H_S + nb]) = hv;
            }
        }
    }
    __syncthreads();

    // ======== dir layer + sigma (MFMA, K=256) ========
    float4v accd[2][4];
    float4v accs[4];
    {
        #pragma unroll
        for (int nt = 0; nt < 2; ++nt)
            #pragma unroll
            for (int st = 0; st < 4; ++st) accd[nt][st] = float4v{0.f, 0.f, 0.f, 0.f};
        #pragma unroll
        for (int st = 0; st < 4; ++st) accs[st] = float4v{0.f, 0.f, 0.f, 0.f};

        for (int ks = 0; ks < 8; ++ks) {
            half8 h[4];
            #pragma unroll
            for (int st = 0; st < 4; ++st)
                h[st] = *reinterpret_cast<const half8*>(&hbuf[(st * 16 + lr) * H_S + ks * 32 + lq * 8]);
            #pragma unroll
            for (int nt = 0; nt < 2; ++nt) {
                const int tile = wv * 2 + nt;
                const half8 w = PACKED
                    ? wp8[(WDP_OFF >> 3) + (ks * 9 + tile) * 64 + lane]
                    : bf_w(w_dir, HID_DIR, ks * 32 + lq * 8, tile * 16 + lr, 1 << 30);
                #pragma unroll
                for (int st = 0; st < 4; ++st)
                    accd[nt][st] = __builtin_amdgcn_mfma_f32_16x16x32_f16(w, h[st], accd[nt][st], 0, 0, 0);
            }
            if (wv == 0) {
                const half8 w = PACKED
                    ? wp8[(WDP_OFF >> 3) + (ks * 9 + 8) * 64 + lane]
                    : bf_sig(w_sig, ks * 32 + lq * 8, lr);
                #pragma unroll
                for (int st = 0; st < 4; ++st)
                    accs[st] = __builtin_amdgcn_mfma_f32_16x16x32_f16(w, h[st], accs[st], 0, 0, 0);
            }
        }
    }
    __syncthreads();   // all H2 reads complete

    // HD -> hbuf (HD_S layout, b64 writes); sigma row 0 -> sigb
    #pragma unroll
    for (int nt = 0; nt < 2; ++nt) {
        const int nb = (wv * 2 + nt) * 16 + lq * 4;
        const float4v db4 = *reinterpret_cast<const float4v*>(&dbv[nb]);
        #pragma unroll
        for (int st = 0; st < 4; ++st) {
            half4v hv;
            #pragma unroll
            for (int r = 0; r < 4; ++r)
                hv[r] = (_Float16)fmaxf(accd[nt][st][r] + db4[r], 0.0f);
            *reinterpret_cast<half4v*>(&hbuf[(st * 16 + lr) * HD_S + nb]) = hv;
        }
    }
    if (wv == 0 && lq == 0) {
        const float bs = b_sig[0];
        #pragma unroll
        for (int st = 0; st < 4; ++st)
            sigb[st * 16 + lr] = accs[st][0] + bs;
    }
    __syncthreads();

    // ======== rgb head (MFMA): wave wv handles sample-tile wv ========
    {
        float4v accr = float4v{0.f, 0.f, 0.f, 0.f};
        #pragma unroll
        for (int ks = 0; ks < 4; ++ks) {
            const half8 h = *reinterpret_cast<const half8*>(&hbuf[(wv * 16 + lr) * HD_S + ks * 32 + lq * 8]);
            const half8 w = PACKED
                ? wp8[(WRGB_OFF >> 3) + ks * 64 + lane]
                : bf_rgb(w_rgb, ks * 32 + lq * 8, lr);
            accr = __builtin_amdgcn_mfma_f32_16x16x32_f16(w, h, accr, 0, 0, 0);
        }
        if (lq == 0) {
            #pragma unroll
            for (int r = 0; r < 3; ++r) {
                const float a = accr[r] + b_rgb[r];
                rgbb[(wv * 16 + lr) * 3 + r] = 1.0f / (1.0f + expf(-a));
            }
        }
    }
    __syncthreads();

    // ======== conditional f64 razor for sigma[63] (aliases dead encH) ========
    if (fabsf(sigb[63]) < 0.02f) {
        {
            const double z63 = zd[63];
            const double p0 = (double)ro0 + (double)rd0 * z63;
            const double p1 = (double)ro1 + (double)rd1 * z63;
            const double p2 = (double)ro2 + (double)rd2 * z63;
            if (tid < D_PTS) {
                const int f = tid;
                double v;
                if (f < 3) {
                    v = (f == 0) ? p0 : ((f == 1) ? p1 : p2);
                } else {
                    const int ff = f - 3;
                    const int l = ff / 6;
                    const int r = ff - 6 * l;
                    const int c = r % 3;
                    const double x = ((c == 0) ? p0 : ((c == 1) ? p1 : p2)) * (double)(1 << l);
                    v = (r < 3) ? sin(x) : cos(x);
                }
                encD[f] = v;
            }
        }
        __syncthreads();
        {
            double acc = 0.0;
            for (int k = 0; k < D_PTS; ++k)
                acc += encD[k] * (double)w1[k * HID + tid];
            acc += (double)b1[tid];
            h1d[tid] = fmax(acc, 0.0);
        }
        __syncthreads();
        {
            double acc = 0.0;
            for (int k = 0; k < HID; ++k)
                acc += h1d[k] * (double)w2[k * HID + tid];
            acc += (double)b2[tid];
            h2d[tid] = fmax(acc, 0.0);
        }
        __syncthreads();
        if (tid < 64) {
            double p = 0.0;
            #pragma unroll
            for (int m = 0; m < 4; ++m)
                p += h2d[tid * 4 + m] * (double)w_sig[tid * 4 + m];
            #pragma unroll
            for (int off = 1; off < 64; off <<= 1)
                p += __shfl_xor(p, off, 64);
            if (tid == 0) sigb[63] = (float)(p + (double)b_sig[0]);
        }
    }
    __syncthreads();

    // ======== volume compositing (wave 0) ========
    if (tid < NS) {
        const int s = tid;
        const float sgv = sigb[s];
        const float zv  = zbuf[s];
        const float zn  = (s < 63) ? zbuf[s + 1] : 0.0f;
        const float dist = (s < 63) ? (zn - zv) : 1.0e10f;
        const float alpha = 1.0f - expf(-fmaxf(sgv, 0.0f) * dist * nrm);
        float P = 1.0f - alpha;
        #pragma unroll
        for (int off = 1; off < 64; off <<= 1) {
            const float p = __shfl_up(P, off, 64);
            if (s >= off) P *= p;
        }
        float T = __shfl_up(P, 1, 64);
        if (s == 0) T = 1.0f;
        const float wgt = alpha * T;
        float r0 = wgt * rgbb[s * 3 + 0];
        float r1 = wgt * rgbb[s * 3 + 1];
        float r2 = wgt * rgbb[s * 3 + 2];
        #pragma unroll
        for (int off = 32; off > 0; off >>= 1) {
            r0 += __shfl_xor(r0, off, 64);
            r1 += __shfl_xor(r1, off, 64);
            r2 += __shfl_xor(r2, off, 64);
        }
        if (s == 0) {
            out[ray * 3 + 0] = r0;
            out[ray * 3 + 1] = r1;
            out[ray * 3 + 2] = r2;
        }
    }
}

} // namespace

extern "C" void kernel_launch(void* const* d_in, const int* in_sizes, int n_in,
                              void* d_out, int out_size, void* d_ws, size_t ws_size,
                              hipStream_t stream) {
    const float* c2w    = (const float*)d_in[0];
    const float* t_rand = (const float*)d_in[1];
    const float* w1     = (const float*)d_in[2];
    const float* b1     = (const float*)d_in[3];
    const float* w2     = (const float*)d_in[4];
    const float* b2     = (const float*)d_in[5];
    const float* w_sig  = (const float*)d_in[6];
    const float* b_sig  = (const float*)d_in[7];
    const float* w_dir  = (const float*)d_in[8];
    const float* b_dir  = (const float*)d_in[9];
    const float* w_rgb  = (const float*)d_in[10];
    const float* b_rgb  = (const float*)d_in[11];

    (void)in_sizes; (void)n_in; (void)out_size;

    const bool packed = (ws_size >= (size_t)(WPACK_HALFS * 2));
    if (packed) {
        _Float16* wp = (_Float16*)d_ws;
        hipLaunchKernelGGL(prepack, dim3((WPACK_HALFS + NTH - 1) / NTH), dim3(NTH), 0, stream,
                           w1, w2, w_dir, w_sig, w_rgb, wp);
        hipLaunchKernelGGL((nerf_fused<true>), dim3(100 * 100), dim3(NTH), 0, stream,
                           c2w, t_rand, w1, b1, w2, b2, w_sig, b_sig,
                           w_dir, b_dir, w_rgb, b_rgb, (const _Float16*)wp, (float*)d_out);
    } else {
        hipLaunchKernelGGL((nerf_fused<false>), dim3(100 * 100), dim3(NTH), 0, stream,
                           c2w, t_rand, w1, b1, w2, b2, w_sig, b_sig,
                           w_dir, b_dir, w_rgb, b_rgb, (const _Float16*)nullptr, (float*)d_out);
    }
}

// Round 16
// 292.122 us; speedup vs baseline: 1.0754x; 1.0754x over previous
//
#include <hip/hip_runtime.h>
#include <cstdint>
#include <cmath>

#define NTH 256

namespace {

typedef _Float16 half8  __attribute__((ext_vector_type(8)));
typedef _Float16 half4v __attribute__((ext_vector_type(4)));
typedef float    float4v __attribute__((ext_vector_type(4)));

constexpr int IMG_W   = 100;
constexpr int NS      = 64;
constexpr int D_PTS   = 63;
constexpr int D_DIR   = 27;
constexpr int HID     = 256;
constexpr int HID_DIR = 128;

constexpr int ENC_H = 72;    // enc stride (halfs), 144B rows (16B-aligned, bank-staggered)
constexpr int H_S   = 264;   // hbuf stride (halfs), 528B rows
constexpr int HD_S  = 136;   // hd stride (halfs)

// Packed fragments [ks][tile][lane][8] (identical lane data for A- or B-side).
constexpr int W1P_OFF  = 0;
constexpr int W2P_OFF  = 16384;
constexpr int WDP_OFF  = 81920;
constexpr int WRGB_OFF = 118784;
constexpr int WPACK_HALFS = 120832;    // 241664 bytes

__global__ __launch_bounds__(NTH)
void prepack(const float* __restrict__ w1, const float* __restrict__ w2,
             const float* __restrict__ wd, const float* __restrict__ wsig,
             const float* __restrict__ wrgb, _Float16* __restrict__ wp)
{
    const int idx = blockIdx.x * NTH + threadIdx.x;
    if (idx >= WPACK_HALFS) return;
    const int j    = idx & 7;
    const int lane = (idx >> 3) & 63;
    const int kloc = (lane >> 4) * 8 + j;
    const int lr   = lane & 15;
    float v = 0.0f;
    if (idx < W2P_OFF) {                               // w1 (K pad 63->64)
        const int nt = (idx >> 9) & 15, ks = idx >> 13;
        const int k = ks * 32 + kloc;
        if (k < D_PTS) v = w1[k * HID + nt * 16 + lr];
    } else if (idx < WDP_OFF) {                        // w2
        const int t = idx - W2P_OFF;
        const int nt = (t >> 9) & 15, ks = t >> 13;
        v = w2[(ks * 32 + kloc) * HID + nt * 16 + lr];
    } else if (idx < WRGB_OFF) {                       // w_dir (K=256) + sigma col
        const int t = idx - WDP_OFF;
        const int q = t >> 9;
        const int ks = q / 9, tile = q - 9 * ks;
        const int k = ks * 32 + kloc;
        if (tile < 8) v = wd[k * HID_DIR + tile * 16 + lr];
        else if (lr == 0) v = wsig[k];
    } else {                                           // w_rgb (N=3 in 16-tile)
        const int t = idx - WRGB_OFF;
        const int ks = t >> 9;
        const int k = ks * 32 + kloc;
        if (lr < 3) v = wrgb[k * 3 + lr];
    }
    wp[idx] = (_Float16)v;
}

// Fallback gathers (no workspace).
__device__ __forceinline__ half8 bf_w(const float* __restrict__ W, int ldN,
                                      int kbase, int n, int kmax) {
    half8 b;
    #pragma unroll
    for (int j = 0; j < 8; ++j) {
        const int k = kbase + j;
        b[j] = (_Float16)((k < kmax) ? W[k * ldN + n] : 0.0f);
    }
    return b;
}
__device__ __forceinline__ half8 bf_sig(const float* __restrict__ ws, int kbase, int lr) {
    half8 b;
    #pragma unroll
    for (int j = 0; j < 8; ++j)
        b[j] = (_Float16)((lr == 0) ? ws[kbase + j] : 0.0f);
    return b;
}
__device__ __forceinline__ half8 bf_rgb(const float* __restrict__ wr, int kbase, int lr) {
    half8 b;
    #pragma unroll
    for (int j = 0; j < 8; ++j)
        b[j] = (_Float16)((lr < 3) ? wr[(kbase + j) * 3 + lr] : 0.0f);
    return b;
}

template<bool PACKED>
__global__ __launch_bounds__(NTH, 4)
void nerf_fused(const float* __restrict__ c2w,
                const float* __restrict__ t_rand,
                const float* __restrict__ w1,  const float* __restrict__ b1,
                const float* __restrict__ w2,  const float* __restrict__ b2,
                const float* __restrict__ w_sig, const float* __restrict__ b_sig,
                const float* __restrict__ w_dir, const float* __restrict__ b_dir,
                const float* __restrict__ w_rgb, const float* __restrict__ b_rgb,
                const _Float16* __restrict__ wpack,
                float* __restrict__ out)
{
    // One shared arena, time-multiplexed (barrier-separated):
    //   phase E  : encH  (64 x ENC_H halfs = 9216 B)     [enc fill + L1 reads]
    //   phase H  : hbuf  (64 x H_S  halfs = 33792 B)     [H1 -> H2 -> HD]
    //   phase R  : razor f64 buffers (4608 B)            [after rgb]
    __shared__ __align__(16) unsigned char scr[NS * H_S * 2];          // 33792 B
    _Float16* encH = reinterpret_cast<_Float16*>(scr);
    _Float16* hbuf = reinterpret_cast<_Float16*>(scr);
    double*   encD = reinterpret_cast<double*>(scr);                   //  512 B
    double*   h1d  = reinterpret_cast<double*>(scr + 512);             // 2048 B
    double*   h2d  = reinterpret_cast<double*>(scr + 2560);            // 2048 B
    __shared__ __align__(16) float dbv[HID_DIR];
    __shared__ float  zbuf[NS];
    __shared__ double zd[NS];
    __shared__ float  encdir[32];
    __shared__ float  sigb[NS];
    __shared__ float  rgbb[NS * 3];

    const int tid  = threadIdx.x;
    const int ray  = blockIdx.x;
    const int lane = tid & 63;
    const int wv   = tid >> 6;
    const int lr   = lane & 15;
    const int lq   = lane >> 4;

    const half8* wp8 = reinterpret_cast<const half8*>(wpack);

    // ---- per-ray setup ----
    const int pj = ray / IMG_W;
    const int pi = ray - pj * IMG_W;
    const float dx = ((float)pi - 50.0f) / 86.6f;
    const float dy = -(((float)pj) - 50.0f) / 86.6f;
    const float rd0 = dx * c2w[0] + dy * c2w[1] - c2w[2];
    const float rd1 = dx * c2w[4] + dy * c2w[5] - c2w[6];
    const float rd2 = dx * c2w[8] + dy * c2w[9] - c2w[10];
    const float ro0 = c2w[3], ro1 = c2w[7], ro2 = c2w[11];
    const float nrm = sqrtf(rd0 * rd0 + rd1 * rd1 + rd2 * rd2);
    const float vd0 = rd0 / nrm, vd1 = rd1 / nrm, vd2 = rd2 / nrm;

    // ---- z: np.linspace-style f64 chain (t[63]=1 exact) ----
    if (tid < NS) {
        const int s = tid;
        const double delta = 1.0 / 63.0;
        const double ts = (s == 63) ? 1.0 : (double)s * delta;
        const double zs = 2.0 * (1.0 - ts) + 6.0 * ts;
        double lower, upper;
        if (s == 0) { lower = zs; }
        else { const double tm = (double)(s - 1) * delta;
               const double zm = 2.0 * (1.0 - tm) + 6.0 * tm; lower = 0.5 * (zm + zs); }
        if (s == 63) { upper = zs; }
        else { const double tp = (s + 1 == 63) ? 1.0 : (double)(s + 1) * delta;
               const double zp = 2.0 * (1.0 - tp) + 6.0 * tp; upper = 0.5 * (zs + zp); }
        const double zz = lower + (upper - lower) * (double)t_rand[s];
        zd[s]   = zz;
        zbuf[s] = (float)zz;
    }
    if (tid < 32) {
        float v = 0.0f;
        if (tid < D_DIR) {
            const int f = tid;
            if (f < 3) {
                v = (f == 0) ? vd0 : ((f == 1) ? vd1 : vd2);
            } else {
                const int ff = f - 3;
                const int l = ff / 6;
                const int r = ff - 6 * l;
                const int c = r % 3;
                const float x = ((c == 0) ? vd0 : ((c == 1) ? vd1 : vd2)) * (float)(1 << l);
                v = (r < 3) ? sinf(x) : cosf(x);
            }
        }
        encdir[tid] = v;
    }
    __syncthreads();

    // ---- enc_pts via double-angle recurrence -> encH (phase E) ----
    if (tid < 192) {
        const int s = tid / 3;
        const int c = tid - 3 * s;
        const float zv = zbuf[s];
        const float p = (c == 0) ? (ro0 + rd0 * zv) : ((c == 1) ? (ro1 + rd1 * zv) : (ro2 + rd2 * zv));
        _Float16* row = &encH[s * ENC_H];
        row[c] = (_Float16)p;
        float sl = sinf(p), cl = cosf(p);
        row[3 + c] = (_Float16)sl;
        row[6 + c] = (_Float16)cl;
        #pragma unroll
        for (int l = 1; l < 10; ++l) {
            const float s2 = 2.0f * sl * cl;
            const float c2 = 1.0f - 2.0f * sl * sl;
            row[3 + 6 * l + c]     = (_Float16)s2;
            row[3 + 6 * l + 3 + c] = (_Float16)c2;
            sl = s2; cl = c2;
        }
    }
    if (tid < 64) encH[tid * ENC_H + 63] = (_Float16)0.0f;   // K-pad col
    // dir tail + bias (ray-uniform)
    if (tid < HID_DIR) {
        float d = b_dir[tid];
        for (int t = 0; t < D_DIR; ++t)
            d += encdir[t] * w_dir[(HID + t) * HID_DIR + tid];
        dbv[tid] = d;
    }
    __syncthreads();

    // ======== layer 1 (MFMA, swapped operands): C'[neuron][sample] ========
    {
        float4v acc[4][4];   // [nt][st]
        #pragma unroll
        for (int nt = 0; nt < 4; ++nt)
            #pragma unroll
            for (int st = 0; st < 4; ++st) acc[nt][st] = float4v{0.f, 0.f, 0.f, 0.f};

        #pragma unroll
        for (int ks = 0; ks < 2; ++ks) {
            half8 h[4];
            #pragma unroll
            for (int st = 0; st < 4; ++st)
                h[st] = *reinterpret_cast<const half8*>(&encH[(st * 16 + lr) * ENC_H + ks * 32 + lq * 8]);
            #pragma unroll
            for (int nt = 0; nt < 4; ++nt) {
                const int tile = wv * 4 + nt;
                const half8 w = PACKED
                    ? wp8[(W1P_OFF >> 3) + (ks * 16 + tile) * 64 + lane]
                    : bf_w(w1, HID, ks * 32 + lq * 8, tile * 16 + lr, D_PTS);
                #pragma unroll
                for (int st = 0; st < 4; ++st)
                    acc[nt][st] = __builtin_amdgcn_mfma_f32_16x16x32_f16(w, h[st], acc[nt][st], 0, 0, 0);
            }
        }
        __syncthreads();   // ALL encH reads complete (hbuf aliases encH)
        #pragma unroll
        for (int nt = 0; nt < 4; ++nt) {
            const int nb = (wv * 4 + nt) * 16 + lq * 4;
            const float4v bb = *reinterpret_cast<const float4v*>(&b1[nb]);
            #pragma unroll
            for (int st = 0; st < 4; ++st) {
                half4v hv;
                #pragma unroll
                for (int r = 0; r < 4; ++r)
                    hv[r] = (_Float16)fmaxf(acc[nt][st][r] + bb[r], 0.0f);
                *reinterpret_cast<half4v*>(&hbuf[(st * 16 + lr) * H_S + nb]) = hv;
            }
        }
    }
    __syncthreads();

    // ======== layer 2 (MFMA): H2 = relu(H1 @ w2 + b2) ========
    {
        float4v acc[4][4];
        #pragma unroll
        for (int nt = 0; nt < 4; ++nt)
            #pragma unroll
            for (int st = 0; st < 4; ++st) acc[nt][st] = float4v{0.f, 0.f, 0.f, 0.f};

        for (int ks = 0; ks < 8; ++ks) {
            half8 h[4];
            #pragma unroll
            for (int st = 0; st < 4; ++st)
                h[st] = *reinterpret_cast<const half8*>(&hbuf[(st * 16 + lr) * H_S + ks * 32 + lq * 8]);
            #pragma unroll
            for (int nt = 0; nt < 4; ++nt) {
                const int tile = wv * 4 + nt;
                const half8 w = PACKED
                    ? wp8[(W2P_OFF >> 3) + (ks * 16 + tile) * 64 + lane]
                    : bf_w(w2, HID, ks * 32 + lq * 8, tile * 16 + lr, 1 << 30);
                #pragma unroll
                for (int st = 0; st < 4; ++st)
                    acc[nt][st] = __builtin_amdgcn_mfma_f32_16x16x32_f16(w, h[st], acc[nt][st], 0, 0, 0);
            }
        }
        __syncthreads();   // all H1 reads complete before in-place overwrite
        #pragma unroll
        for (int nt = 0; nt < 4; ++nt) {
            const int nb = (wv * 4 + nt) * 16 + lq * 4;
            const float4v bb = *reinterpret_cast<const float4v*>(&b2[nb]);
            #pragma unroll
            for (int st = 0; st < 4; ++st) {
                half4v hv;
                #pragma unroll
                for (int r = 0; r < 4; ++r)
                    hv[r] = (_Float16)fmaxf(acc[nt][st][r] + bb[r], 0.0f);
                *reinterpret_cast<half4v*>(&hbuf[(st * 16 + lr) * H_S + nb]) = hv;
            }
        }
    }
    __syncthreads();

    // ======== dir layer + sigma (MFMA, K=256) ========
    float4v accd[2][4];
    float4v accs[4];
    {
        #pragma unroll
        for (int nt = 0; nt < 2; ++nt)
            #pragma unroll
            for (int st = 0; st < 4; ++st) accd[nt][st] = float4v{0.f, 0.f, 0.f, 0.f};
        #pragma unroll
        for (int st = 0; st < 4; ++st) accs[st] = float4v{0.f, 0.f, 0.f, 0.f};

        for (int ks = 0; ks < 8; ++ks) {
            half8 h[4];
            #pragma unroll
            for (int st = 0; st < 4; ++st)
                h[st] = *reinterpret_cast<const half8*>(&hbuf[(st * 16 + lr) * H_S + ks * 32 + lq * 8]);
            #pragma unroll
            for (int nt = 0; nt < 2; ++nt) {
                const int tile = wv * 2 + nt;
                const half8 w = PACKED
                    ? wp8[(WDP_OFF >> 3) + (ks * 9 + tile) * 64 + lane]
                    : bf_w(w_dir, HID_DIR, ks * 32 + lq * 8, tile * 16 + lr, 1 << 30);
                #pragma unroll
                for (int st = 0; st < 4; ++st)
                    accd[nt][st] = __builtin_amdgcn_mfma_f32_16x16x32_f16(w, h[st], accd[nt][st], 0, 0, 0);
            }
            if (wv == 0) {
                const half8 w = PACKED
                    ? wp8[(WDP_OFF >> 3) + (ks * 9 + 8) * 64 + lane]
                    : bf_sig(w_sig, ks * 32 + lq * 8, lr);
                #pragma unroll
                for (int st = 0; st < 4; ++st)
                    accs[st] = __builtin_amdgcn_mfma_f32_16x16x32_f16(w, h[st], accs[st], 0, 0, 0);
            }
        }
    }
    __syncthreads();   // all H2 reads complete

    // HD -> hbuf (HD_S layout); sigma row 0 -> sigb
    #pragma unroll
    for (int nt = 0; nt < 2; ++nt) {
        const int nb = (wv * 2 + nt) * 16 + lq * 4;
        const float4v db4 = *reinterpret_cast<const float4v*>(&dbv[nb]);
        #pragma unroll
        for (int st = 0; st < 4; ++st) {
            half4v hv;
            #pragma unroll
            for (int r = 0; r < 4; ++r)
                hv[r] = (_Float16)fmaxf(accd[nt][st][r] + db4[r], 0.0f);
            *reinterpret_cast<half4v*>(&hbuf[(st * 16 + lr) * HD_S + nb]) = hv;
        }
    }
    if (wv == 0 && lq == 0) {
        const float bs = b_sig[0];
        #pragma unroll
        for (int st = 0; st < 4; ++st)
            sigb[st * 16 + lr] = accs[st][0] + bs;
    }
    __syncthreads();

    // ======== rgb head (MFMA): wave wv handles sample-tile wv ========
    {
        float4v accr = float4v{0.f, 0.f, 0.f, 0.f};
        #pragma unroll
        for (int ks = 0; ks < 4; ++ks) {
            const half8 h = *reinterpret_cast<const half8*>(&hbuf[(wv * 16 + lr) * HD_S + ks * 32 + lq * 8]);
            const half8 w = PACKED
                ? wp8[(WRGB_OFF >> 3) + ks * 64 + lane]
                : bf_rgb(w_rgb, ks * 32 + lq * 8, lr);
            accr = __builtin_amdgcn_mfma_f32_16x16x32_f16(w, h, accr, 0, 0, 0);
        }
        if (lq == 0) {
            #pragma unroll
            for (int r = 0; r < 3; ++r) {
                const float a = accr[r] + b_rgb[r];
                rgbb[(wv * 16 + lr) * 3 + r] = 1.0f / (1.0f + expf(-a));
            }
        }
    }
    __syncthreads();   // rgb reads done -> scr reusable by razor

    // ======== conditional f64 razor for sigma[63] (aliases scr) ========
    if (fabsf(sigb[63]) < 0.02f) {
        {
            const double z63 = zd[63];
            const double p0 = (double)ro0 + (double)rd0 * z63;
            const double p1 = (double)ro1 + (double)rd1 * z63;
            const double p2 = (double)ro2 + (double)rd2 * z63;
            if (tid < D_PTS) {
                const int f = tid;
                double v;
                if (f < 3) {
                    v = (f == 0) ? p0 : ((f == 1) ? p1 : p2);
                } else {
                    const int ff = f - 3;
                    const int l = ff / 6;
                    const int r = ff - 6 * l;
                    const int c = r % 3;
                    const double x = ((c == 0) ? p0 : ((c == 1) ? p1 : p2)) * (double)(1 << l);
                    v = (r < 3) ? sin(x) : cos(x);
                }
                encD[f] = v;
            }
        }
        __syncthreads();
        {
            double acc = 0.0;
            for (int k = 0; k < D_PTS; ++k)
                acc += encD[k] * (double)w1[k * HID + tid];
            acc += (double)b1[tid];
            h1d[tid] = fmax(acc, 0.0);
        }
        __syncthreads();
        {
            double acc = 0.0;
            for (int k = 0; k < HID; ++k)
                acc += h1d[k] * (double)w2[k * HID + tid];
            acc += (double)b2[tid];
            h2d[tid] = fmax(acc, 0.0);
        }
        __syncthreads();
        if (tid < 64) {
            double p = 0.0;
            #pragma unroll
            for (int m = 0; m < 4; ++m)
                p += h2d[tid * 4 + m] * (double)w_sig[tid * 4 + m];
            #pragma unroll
            for (int off = 1; off < 64; off <<= 1)
                p += __shfl_xor(p, off, 64);
            if (tid == 0) sigb[63] = (float)(p + (double)b_sig[0]);
        }
    }
    __syncthreads();

    // ======== volume compositing (wave 0) ========
    if (tid < NS) {
        const int s = tid;
        const float sgv = sigb[s];
        const float zv  = zbuf[s];
        const float zn  = (s < 63) ? zbuf[s + 1] : 0.0f;
        const float dist = (s < 63) ? (zn - zv) : 1.0e10f;
        const float alpha = 1.0f - expf(-fmaxf(sgv, 0.0f) * dist * nrm);
        float P = 1.0f - alpha;
        #pragma unroll
        for (int off = 1; off < 64; off <<= 1) {
            const float p = __shfl_up(P, off, 64);
            if (s >= off) P *= p;
        }
        float T = __shfl_up(P, 1, 64);
        if (s == 0) T = 1.0f;
        const float wgt = alpha * T;
        float r0 = wgt * rgbb[s * 3 + 0];
        float r1 = wgt * rgbb[s * 3 + 1];
        float r2 = wgt * rgbb[s * 3 + 2];
        #pragma unroll
        for (int off = 32; off > 0; off >>= 1) {
            r0 += __shfl_xor(r0, off, 64);
            r1 += __shfl_xor(r1, off, 64);
            r2 += __shfl_xor(r2, off, 64);
        }
        if (s == 0) {
            out[ray * 3 + 0] = r0;
            out[ray * 3 + 1] = r1;
            out[ray * 3 + 2] = r2;
        }
    }
}

} // namespace

extern "C" void kernel_launch(void* const* d_in, const int* in_sizes, int n_in,
                              void* d_out, int out_size, void* d_ws, size_t ws_size,
                              hipStream_t stream) {
    const float* c2w    = (const float*)d_in[0];
    const float* t_rand = (const float*)d_in[1];
    const float* w1     = (const float*)d_in[2];
    const float* b1     = (const float*)d_in[3];
    const float* w2     = (const float*)d_in[4];
    const float* b2     = (const float*)d_in[5];
    const float* w_sig  = (const float*)d_in[6];
    const float* b_sig  = (const float*)d_in[7];
    const float* w_dir  = (const float*)d_in[8];
    const float* b_dir  = (const float*)d_in[9];
    const float* w_rgb  = (const float*)d_in[10];
    const float* b_rgb  = (const float*)d_in[11];

    (void)in_sizes; (void)n_in; (void)out_size;

    const bool packed = (ws_size >= (size_t)(WPACK_HALFS * 2));
    if (packed) {
        _Float16* wp = (_Float16*)d_ws;
        hipLaunchKernelGGL(prepack, dim3((WPACK_HALFS + NTH - 1) / NTH), dim3(NTH), 0, stream,
                           w1, w2, w_dir, w_sig, w_rgb, wp);
        hipLaunchKernelGGL((nerf_fused<true>), dim3(100 * 100), dim3(NTH), 0, stream,
                           c2w, t_rand, w1, b1, w2, b2, w_sig, b_sig,
                           w_dir, b_dir, w_rgb, b_rgb, (const _Float16*)wp, (float*)d_out);
    } else {
        hipLaunchKernelGGL((nerf_fused<false>), dim3(100 * 100), dim3(NTH), 0, stream,
                           c2w, t_rand, w1, b1, w2, b2, w_sig, b_sig,
                           w_dir, b_dir, w_rgb, b_rgb, (const _Float16*)nullptr, (float*)d_out);
    }
}